// Round 7
// baseline (10215.076 us; speedup 1.0000x reference)
//
#include <hip/hip_runtime.h>
#include <hip/hip_bf16.h>

typedef __hip_bfloat16 bf16;

#define E_DIM 1024
#define H_NUM 16
#define DH_DIM 64
#define DFF_DIM 4096
#define B_SZ 4
#define S_LEN 512
#define NTOK 2048   // B*S

// ---------------- transpose in: (S,B,E) f32 -> (B,S,E) f32 ----------------
__global__ __launch_bounds__(256) void transpose_in(const float* __restrict__ in,
                                                    float* __restrict__ out) {
    size_t i = (size_t)blockIdx.x * 256 + threadIdx.x;  // over S*B*E
    int e = (int)(i & 1023);
    int sb = (int)(i >> 10);          // s*B + b
    int b = sb & 3;
    int s = sb >> 2;
    out[((size_t)((b << 9) + s) << 10) + e] = in[i];
}

// ---------------- writeout: (B,S,E) f32 -> (S,B,E) f32 (output IS f32!) ------
__global__ __launch_bounds__(256) void writeout(const float* __restrict__ y,
                                                float* __restrict__ out) {
    size_t i = (size_t)blockIdx.x * 256 + threadIdx.x;  // over S*B*E (out order)
    int e = (int)(i & 1023);
    int sb = (int)(i >> 10);          // s*B + b
    int b = sb & 3;
    int s = sb >> 2;
    out[i] = y[((size_t)((b << 9) + s) << 10) + e];
}

// ---------------- GEMM: C[M,N] = A[M,K](f32) @ W[K,N](f32) (+bias)(relu)(+res) ----
// QKV layout: W element (k,n) at (n>>6)*(K*64) + k*64 + (n&63)
template<bool QKV, bool RELU, bool BIAS, bool RES>
__global__ __launch_bounds__(256) void gemm_kernel(
    const float* __restrict__ A, int lda,
    const float* __restrict__ W, int ldw,
    const float* __restrict__ bias,
    const float* __restrict__ Res, int ldres,
    float* __restrict__ C, int ldc,
    int M, int N, int K)
{
    __shared__ float As[16][72];  // [k][m], padded
    __shared__ float Ws[16][64];  // [k][n]
    const int tid = threadIdx.x;
    const int tx = tid & 15;      // col group
    const int ty = tid >> 4;      // row group
    const int row0 = blockIdx.y * 64 + ty * 4;
    const int col0 = blockIdx.x * 64 + tx * 4;
    float acc[4][4] = {};

    for (int k0 = 0; k0 < K; k0 += 16) {
        #pragma unroll
        for (int r = 0; r < 4; ++r) {
            int i = tid + r * 256;
            int m = i >> 4;
            int kk = i & 15;
            As[kk][m] = A[(size_t)(blockIdx.y * 64 + m) * lda + k0 + kk];
        }
        #pragma unroll
        for (int r = 0; r < 4; ++r) {
            int i = tid + r * 256;
            int kk = i >> 6;
            int n = i & 63;
            int gn = blockIdx.x * 64 + n;
            size_t widx;
            if (QKV) widx = (size_t)(gn >> 6) * ((size_t)K * 64) + (size_t)(k0 + kk) * 64 + (gn & 63);
            else     widx = (size_t)(k0 + kk) * ldw + gn;
            Ws[kk][n] = W[widx];
        }
        __syncthreads();
        #pragma unroll
        for (int kk = 0; kk < 16; ++kk) {
            float a[4], bb[4];
            #pragma unroll
            for (int i = 0; i < 4; ++i) a[i] = As[kk][ty * 4 + i];
            #pragma unroll
            for (int j = 0; j < 4; ++j) bb[j] = Ws[kk][tx * 4 + j];
            #pragma unroll
            for (int i = 0; i < 4; ++i)
                #pragma unroll
                for (int j = 0; j < 4; ++j)
                    acc[i][j] = fmaf(a[i], bb[j], acc[i][j]);
        }
        __syncthreads();
    }

    #pragma unroll
    for (int i = 0; i < 4; ++i) {
        int m = row0 + i;
        #pragma unroll
        for (int j = 0; j < 4; ++j) {
            int n = col0 + j;
            float v = acc[i][j];
            if (BIAS) v += bias[n];
            if (RELU) v = fmaxf(v, 0.0f);
            if (RES)  v += Res[(size_t)m * ldres + n];
            C[(size_t)m * ldc + n] = v;
        }
    }
}

// ---------------- attention: per-(b,h,16-query tile) block ----------------
// masked where (maskA[s,t] + maskB[b,t]) is -inf (robust: < -1e30)
__global__ __launch_bounds__(256) void attn_kernel(
    const float* __restrict__ Q, int ldq,
    const float* __restrict__ Kb, int ldk,
    const float* __restrict__ Vb, int ldv,
    float* __restrict__ O, int ldo,
    const float* __restrict__ maskA,   // Sq x Sk or null
    const float* __restrict__ maskB,   // B x Sk or null
    int Sq, int Sk, float inv_scale)
{
    __shared__ float sQ[16][64];
    __shared__ float sKV[64][65];
    __shared__ float sP[16][512];
    const int qt = blockIdx.x, h = blockIdx.y, b = blockIdx.z;
    const int tid = threadIdx.x;

    #pragma unroll
    for (int r = 0; r < 4; ++r) {
        int i = tid + r * 256;
        int q = i >> 6, d = i & 63;
        sQ[q][d] = Q[(size_t)(b * Sq + qt * 16 + q) * ldq + h * 64 + d];
    }
    __syncthreads();

    for (int t0 = 0; t0 < Sk; t0 += 64) {
        #pragma unroll
        for (int r = 0; r < 16; ++r) {
            int i = tid + r * 256;
            int t = i >> 6, d = i & 63;
            sKV[t][d] = Kb[(size_t)(b * Sk + t0 + t) * ldk + h * 64 + d];
        }
        __syncthreads();
        #pragma unroll
        for (int j = 0; j < 4; ++j) {
            int p = tid + 256 * j;
            int q = p >> 6, t = p & 63;
            float acc = 0.0f;
            #pragma unroll
            for (int d = 0; d < 64; ++d) acc = fmaf(sQ[q][d], sKV[t][d], acc);
            acc *= inv_scale;
            int tg = t0 + t;
            float mv = 0.0f;
            if (maskA) mv += maskA[(size_t)(qt * 16 + q) * Sk + tg];
            if (maskB) mv += maskB[(size_t)b * Sk + tg];
            bool masked = (mv < -1.0e30f) || (__float_as_uint(mv) == 0xFF800000u);
            sP[q][tg] = masked ? -3.0e38f : acc;
        }
        __syncthreads();
    }

    // softmax: 16 threads per row
    {
        int q = tid >> 4;
        int l = tid & 15;
        float mx = -3.0e38f;
        for (int t = l; t < Sk; t += 16) mx = fmaxf(mx, sP[q][t]);
        #pragma unroll
        for (int off = 8; off; off >>= 1) mx = fmaxf(mx, __shfl_xor(mx, off, 16));
        float sum = 0.0f;
        for (int t = l; t < Sk; t += 16) {
            float x = sP[q][t] - mx;
            float p = (x < -80.0f) ? 0.0f : __expf(x);
            sP[q][t] = p;
            sum += p;
        }
        #pragma unroll
        for (int off = 8; off; off >>= 1) sum += __shfl_xor(sum, off, 16);
        float inv = 1.0f / sum;
        for (int t = l; t < Sk; t += 16) sP[q][t] *= inv;
    }
    __syncthreads();

    // PV
    float oacc[4] = {};
    const int d = tid & 63, qg = tid >> 6;
    for (int t0 = 0; t0 < Sk; t0 += 64) {
        #pragma unroll
        for (int r = 0; r < 16; ++r) {
            int i = tid + r * 256;
            int t = i >> 6, dd = i & 63;
            sKV[t][dd] = Vb[(size_t)(b * Sk + t0 + t) * ldv + h * 64 + dd];
        }
        __syncthreads();
        #pragma unroll 4
        for (int t = 0; t < 64; ++t) {
            float vv = sKV[t][d];
            #pragma unroll
            for (int j = 0; j < 4; ++j)
                oacc[j] = fmaf(sP[qg + 4 * j][t0 + t], vv, oacc[j]);
        }
        __syncthreads();
    }
    #pragma unroll
    for (int j = 0; j < 4; ++j) {
        int q = qg + 4 * j;
        O[(size_t)(b * Sq + qt * 16 + q) * ldo + h * 64 + d] = oacc[j];
    }
}

// ---------------- layernorm (in place, E=1024, one block per row) ------------
__global__ __launch_bounds__(256) void ln_kernel(float* __restrict__ X,
        const float* __restrict__ g, const float* __restrict__ bta) {
    __shared__ float wred[4];
    __shared__ float stat;
    float* x = X + ((size_t)blockIdx.x << 10);
    const int tid = threadIdx.x;
    float4 v = reinterpret_cast<float4*>(x)[tid];
    float s = v.x + v.y + v.z + v.w;
    #pragma unroll
    for (int off = 32; off; off >>= 1) s += __shfl_down(s, off, 64);
    if ((tid & 63) == 0) wred[tid >> 6] = s;
    __syncthreads();
    if (tid == 0) stat = (wred[0] + wred[1] + wred[2] + wred[3]) * (1.0f / 1024.0f);
    __syncthreads();
    float m = stat;
    float dx = v.x - m, dy = v.y - m, dz = v.z - m, dw = v.w - m;
    float s2 = dx * dx + dy * dy + dz * dz + dw * dw;
    #pragma unroll
    for (int off = 32; off; off >>= 1) s2 += __shfl_down(s2, off, 64);
    __syncthreads();
    if ((tid & 63) == 0) wred[tid >> 6] = s2;
    __syncthreads();
    if (tid == 0) stat = rsqrtf((wred[0] + wred[1] + wred[2] + wred[3]) * (1.0f / 1024.0f) + 1e-5f);
    __syncthreads();
    float r = stat;
    const float4 gv = reinterpret_cast<const float4*>(g)[tid];
    const float4 bv = reinterpret_cast<const float4*>(bta)[tid];
    float4 o;
    o.x = dx * r * gv.x + bv.x;
    o.y = dy * r * gv.y + bv.y;
    o.z = dz * r * gv.z + bv.z;
    o.w = dw * r * gv.w + bv.w;
    reinterpret_cast<float4*>(x)[tid] = o;
}

extern "C" void kernel_launch(void* const* d_in, const int* in_sizes, int n_in,
                              void* d_out, int out_size, void* d_ws, size_t ws_size,
                              hipStream_t stream) {
    const float* src      = (const float*)d_in[0];
    const float* tgt      = (const float*)d_in[1];
    const float* src_mask = (const float*)d_in[2];
    const float* tgt_mask = (const float*)d_in[3];
    const float* src_pad  = (const float*)d_in[4];
    const float* tgt_pad  = (const float*)d_in[5];
    const float* enc_wqkv = (const float*)d_in[6];
    const float* enc_wo   = (const float*)d_in[7];
    const float* enc_bo   = (const float*)d_in[8];
    const float* enc_w1   = (const float*)d_in[9];
    const float* enc_b1   = (const float*)d_in[10];
    const float* enc_w2   = (const float*)d_in[11];
    const float* enc_b2   = (const float*)d_in[12];
    const float* enc_lg   = (const float*)d_in[13];
    const float* enc_lb   = (const float*)d_in[14];
    const float* dq_s     = (const float*)d_in[15];
    const float* dwo_s    = (const float*)d_in[16];
    const float* dbo_s    = (const float*)d_in[17];
    const float* dq_c     = (const float*)d_in[18];
    const float* dwo_c    = (const float*)d_in[19];
    const float* dbo_c    = (const float*)d_in[20];
    const float* dw1      = (const float*)d_in[21];
    const float* db1      = (const float*)d_in[22];
    const float* dw2      = (const float*)d_in[23];
    const float* db2      = (const float*)d_in[24];
    const float* dlg      = (const float*)d_in[25];
    const float* dlb      = (const float*)d_in[26];

    // Workspace (48 MB, confirmed available by round-5 meta probe):
    float* xe  = (float*)d_ws;                      // 2048*1024
    float* y   = xe  + (size_t)NTOK * E_DIM;        // 2048*1024
    float* qkv = y   + (size_t)NTOK * E_DIM;        // 2048*3072
    float* att = qkv + (size_t)NTOK * 3 * E_DIM;    // 2048*1024
    float* ffh = qkv;   // FFN hidden aliases qkv+att (dead during FFN)

    const size_t WQKV_L = (size_t)3 * H_NUM * E_DIM * DH_DIM;
    const size_t HED    = (size_t)H_NUM * E_DIM * DH_DIM;
    const dim3 blk(256);

    transpose_in<<<(NTOK * E_DIM) / 256, blk, 0, stream>>>(src, xe);
    transpose_in<<<(NTOK * E_DIM) / 256, blk, 0, stream>>>(tgt, y);

    // -------- encoder --------
    for (int i = 0; i < 4; ++i) {
        gemm_kernel<true, false, false, false><<<dim3(3072 / 64, NTOK / 64), blk, 0, stream>>>(
            xe, E_DIM, enc_wqkv + i * WQKV_L, 0, nullptr, nullptr, 0,
            qkv, 3072, NTOK, 3072, E_DIM);
        attn_kernel<<<dim3(S_LEN / 16, H_NUM, B_SZ), blk, 0, stream>>>(
            qkv, 3072, qkv + 1024, 3072, qkv + 2048, 3072, att, E_DIM,
            src_mask, src_pad, S_LEN, S_LEN, 0.125f);
        gemm_kernel<false, false, true, true><<<dim3(E_DIM / 64, NTOK / 64), blk, 0, stream>>>(
            att, E_DIM, enc_wo + (size_t)i * E_DIM * E_DIM, E_DIM, enc_bo + i * E_DIM,
            xe, E_DIM, xe, E_DIM, NTOK, E_DIM, E_DIM);
        ln_kernel<<<NTOK, blk, 0, stream>>>(xe, enc_lg + (size_t)(i * 2 + 0) * E_DIM,
                                            enc_lb + (size_t)(i * 2 + 0) * E_DIM);
        gemm_kernel<false, true, true, false><<<dim3(DFF_DIM / 64, NTOK / 64), blk, 0, stream>>>(
            xe, E_DIM, enc_w1 + (size_t)i * E_DIM * DFF_DIM, DFF_DIM, enc_b1 + i * DFF_DIM,
            nullptr, 0, ffh, DFF_DIM, NTOK, DFF_DIM, E_DIM);
        gemm_kernel<false, false, true, true><<<dim3(E_DIM / 64, NTOK / 64), blk, 0, stream>>>(
            ffh, DFF_DIM, enc_w2 + (size_t)i * DFF_DIM * E_DIM, E_DIM, enc_b2 + i * E_DIM,
            xe, E_DIM, xe, E_DIM, NTOK, E_DIM, DFF_DIM);
        ln_kernel<<<NTOK, blk, 0, stream>>>(xe, enc_lg + (size_t)(i * 2 + 1) * E_DIM,
                                            enc_lb + (size_t)(i * 2 + 1) * E_DIM);
    }

    // -------- decoder --------
    for (int i = 0; i < 4; ++i) {
        gemm_kernel<true, false, false, false><<<dim3(3072 / 64, NTOK / 64), blk, 0, stream>>>(
            y, E_DIM, dq_s + i * WQKV_L, 0, nullptr, nullptr, 0,
            qkv, 3072, NTOK, 3072, E_DIM);
        attn_kernel<<<dim3(S_LEN / 16, H_NUM, B_SZ), blk, 0, stream>>>(
            qkv, 3072, qkv + 1024, 3072, qkv + 2048, 3072, att, E_DIM,
            tgt_mask, tgt_pad, S_LEN, S_LEN, 0.125f);
        gemm_kernel<false, false, true, true><<<dim3(E_DIM / 64, NTOK / 64), blk, 0, stream>>>(
            att, E_DIM, dwo_s + (size_t)i * E_DIM * E_DIM, E_DIM, dbo_s + i * E_DIM,
            y, E_DIM, y, E_DIM, NTOK, E_DIM, E_DIM);
        ln_kernel<<<NTOK, blk, 0, stream>>>(y, dlg + (size_t)(i * 3 + 0) * E_DIM,
                                            dlb + (size_t)(i * 3 + 0) * E_DIM);
        // cross-attention: q from y; k,v from encoder memory xe
        gemm_kernel<true, false, false, false><<<dim3(E_DIM / 64, NTOK / 64), blk, 0, stream>>>(
            y, E_DIM, dq_c + i * WQKV_L + 0 * HED, 0, nullptr, nullptr, 0,
            qkv, 3072, NTOK, E_DIM, E_DIM);
        gemm_kernel<true, false, false, false><<<dim3(E_DIM / 64, NTOK / 64), blk, 0, stream>>>(
            xe, E_DIM, dq_c + i * WQKV_L + 1 * HED, 0, nullptr, nullptr, 0,
            qkv + 1024, 3072, NTOK, E_DIM, E_DIM);
        gemm_kernel<true, false, false, false><<<dim3(E_DIM / 64, NTOK / 64), blk, 0, stream>>>(
            xe, E_DIM, dq_c + i * WQKV_L + 2 * HED, 0, nullptr, nullptr, 0,
            qkv + 2048, 3072, NTOK, E_DIM, E_DIM);
        attn_kernel<<<dim3(S_LEN / 16, H_NUM, B_SZ), blk, 0, stream>>>(
            qkv, 3072, qkv + 1024, 3072, qkv + 2048, 3072, att, E_DIM,
            nullptr, src_pad, S_LEN, S_LEN, 0.125f);
        gemm_kernel<false, false, true, true><<<dim3(E_DIM / 64, NTOK / 64), blk, 0, stream>>>(
            att, E_DIM, dwo_c + (size_t)i * E_DIM * E_DIM, E_DIM, dbo_c + i * E_DIM,
            y, E_DIM, y, E_DIM, NTOK, E_DIM, E_DIM);
        ln_kernel<<<NTOK, blk, 0, stream>>>(y, dlg + (size_t)(i * 3 + 1) * E_DIM,
                                            dlb + (size_t)(i * 3 + 1) * E_DIM);
        gemm_kernel<false, true, true, false><<<dim3(DFF_DIM / 64, NTOK / 64), blk, 0, stream>>>(
            y, E_DIM, dw1 + (size_t)i * E_DIM * DFF_DIM, DFF_DIM, db1 + i * DFF_DIM,
            nullptr, 0, ffh, DFF_DIM, NTOK, DFF_DIM, E_DIM);
        gemm_kernel<false, false, true, true><<<dim3(E_DIM / 64, NTOK / 64), blk, 0, stream>>>(
            ffh, DFF_DIM, dw2 + (size_t)i * DFF_DIM * E_DIM, E_DIM, db2 + i * E_DIM,
            y, E_DIM, y, E_DIM, NTOK, E_DIM, DFF_DIM);
        ln_kernel<<<NTOK, blk, 0, stream>>>(y, dlg + (size_t)(i * 3 + 2) * E_DIM,
                                            dlb + (size_t)(i * 3 + 2) * E_DIM);
    }

    writeout<<<(NTOK * E_DIM) / 256, blk, 0, stream>>>(y, (float*)d_out);
}

// Round 8
// 9657.311 us; speedup vs baseline: 1.0578x; 1.0578x over previous
//
#include <hip/hip_runtime.h>
#include <hip/hip_bf16.h>

typedef __hip_bfloat16 bf16;
typedef unsigned short u16;
typedef u16 u16x4 __attribute__((ext_vector_type(4)));
typedef u16 u16x8 __attribute__((ext_vector_type(8)));
typedef __bf16 bf16x8 __attribute__((ext_vector_type(8)));
typedef float f32x4 __attribute__((ext_vector_type(4)));

#define E_DIM 1024
#define H_NUM 16
#define DH_DIM 64
#define DFF_DIM 4096
#define B_SZ 4
#define S_LEN 512
#define NTOK 2048   // B*S

__device__ __forceinline__ u16 f2bf(float f) {           // RNE f32->bf16
    unsigned u = __float_as_uint(f);
    return (u16)((u + 0x7FFFu + ((u >> 16) & 1u)) >> 16);
}

// ---------------- transpose in: (S,B,E) f32 -> (B,S,E) f32 ----------------
__global__ __launch_bounds__(256) void transpose_in(const float* __restrict__ in,
                                                    float* __restrict__ out) {
    size_t i = (size_t)blockIdx.x * 256 + threadIdx.x;
    int e = (int)(i & 1023);
    int sb = (int)(i >> 10);
    int b = sb & 3;
    int s = sb >> 2;
    out[((size_t)((b << 9) + s) << 10) + e] = in[i];
}

// ---------------- writeout: (B,S,E) f32 -> (S,B,E) f32 ----------------
__global__ __launch_bounds__(256) void writeout(const float* __restrict__ y,
                                                float* __restrict__ out) {
    size_t i = (size_t)blockIdx.x * 256 + threadIdx.x;
    int e = (int)(i & 1023);
    int sb = (int)(i >> 10);
    int b = sb & 3;
    int s = sb >> 2;
    out[i] = y[((size_t)((b << 9) + s) << 10) + e];
}

// ============ MFMA GEMM: C[M,N] = A[M,K](f32) @ W[K,N](f32->bf16) ============
// Tile BM x 128, BK=32, 4 waves, wave tile (BM/2)x64 as MRx4 16x16 frags.
// LDS: As[BM][40] (row-major k), Bs[128][40] (n-major k) — stride 80B, b128-aligned.
// QKV layout: W element (k,n) at (n>>6)*(K*64) + k*64 + (n&63)
template<int BM, bool QKV, bool RELU, bool BIAS, bool RES>
__global__ __launch_bounds__(256) void gemm_mfma(
    const float* __restrict__ A, int lda,
    const float* __restrict__ W, int ldw,
    const float* __restrict__ bias,
    const float* __restrict__ Res, int ldres,
    float* __restrict__ C, int ldc,
    int M, int N, int K)
{
    constexpr int MR = BM / 32;                 // m-fragments per wave
    __shared__ u16 As[BM * 40];
    __shared__ u16 Bs[128 * 40];
    const int tid = threadIdx.x;
    const int l = tid & 63;
    const int w = tid >> 6;
    const int m0 = blockIdx.y * BM;
    const int n0 = blockIdx.x * 128;
    const int mw = (w >> 1) * (BM / 2);
    const int nw = (w & 1) * 64;
    const int lr = l & 15;                      // frag row/col lane part
    const int lg = l >> 4;                      // k-group

    f32x4 acc[MR][4];
    #pragma unroll
    for (int mi = 0; mi < MR; ++mi)
        #pragma unroll
        for (int ni = 0; ni < 4; ++ni) acc[mi][ni] = (f32x4)(0.0f);

    for (int k0 = 0; k0 < K; k0 += 32) {
        // ---- stage A: BM x 32, float4 along k ----
        #pragma unroll
        for (int r = 0; r < BM / 32; ++r) {
            int idx = tid + r * 256;
            int m = idx >> 3;
            int k4 = idx & 7;
            const float4 av = *reinterpret_cast<const float4*>(
                A + (size_t)(m0 + m) * lda + k0 + k4 * 4);
            u16x4 o; o.x = f2bf(av.x); o.y = f2bf(av.y); o.z = f2bf(av.z); o.w = f2bf(av.w);
            *reinterpret_cast<u16x4*>(&As[m * 40 + k4 * 4]) = o;
        }
        // ---- stage B: 32 x 128 source -> Bs[n][k] (transpose) ----
        #pragma unroll
        for (int r = 0; r < 4; ++r) {
            int idx = tid + r * 256;
            int k = idx >> 5;
            int n4 = idx & 31;
            int gn = n0 + n4 * 4;
            const float* wp = QKV
                ? W + (size_t)(gn >> 6) * ((size_t)K * 64) + (size_t)(k0 + k) * 64 + (gn & 63)
                : W + (size_t)(k0 + k) * ldw + gn;
            const float4 wv = *reinterpret_cast<const float4*>(wp);
            Bs[(n4 * 4 + 0) * 40 + k] = f2bf(wv.x);
            Bs[(n4 * 4 + 1) * 40 + k] = f2bf(wv.y);
            Bs[(n4 * 4 + 2) * 40 + k] = f2bf(wv.z);
            Bs[(n4 * 4 + 3) * 40 + k] = f2bf(wv.w);
        }
        __syncthreads();

        // ---- fragments + MFMA ----
        u16x8 a[MR], b[4];
        #pragma unroll
        for (int mi = 0; mi < MR; ++mi)
            a[mi] = *reinterpret_cast<const u16x8*>(&As[(mw + mi * 16 + lr) * 40 + lg * 8]);
        #pragma unroll
        for (int ni = 0; ni < 4; ++ni)
            b[ni] = *reinterpret_cast<const u16x8*>(&Bs[(nw + ni * 16 + lr) * 40 + lg * 8]);
        #pragma unroll
        for (int mi = 0; mi < MR; ++mi)
            #pragma unroll
            for (int ni = 0; ni < 4; ++ni)
                acc[mi][ni] = __builtin_amdgcn_mfma_f32_16x16x32_bf16(
                    __builtin_bit_cast(bf16x8, a[mi]),
                    __builtin_bit_cast(bf16x8, b[ni]),
                    acc[mi][ni], 0, 0, 0);
        __syncthreads();
    }

    // ---- epilogue (C/D: col = lane&15, row = (lane>>4)*4 + reg) ----
    #pragma unroll
    for (int mi = 0; mi < MR; ++mi) {
        #pragma unroll
        for (int ni = 0; ni < 4; ++ni) {
            int gc = n0 + nw + ni * 16 + lr;
            #pragma unroll
            for (int r = 0; r < 4; ++r) {
                int gr = m0 + mw + mi * 16 + lg * 4 + r;
                float v = acc[mi][ni][r];
                if (BIAS) v += bias[gc];
                if (RELU) v = fmaxf(v, 0.0f);
                if (RES)  v += Res[(size_t)gr * ldres + gc];
                C[(size_t)gr * ldc + gc] = v;
            }
        }
    }
}

// ---------------- attention: per-(b,h,16-query tile) block (f32) ----------
__global__ __launch_bounds__(256) void attn_kernel(
    const float* __restrict__ Q, int ldq,
    const float* __restrict__ Kb, int ldk,
    const float* __restrict__ Vb, int ldv,
    float* __restrict__ O, int ldo,
    const float* __restrict__ maskA,   // Sq x Sk or null
    const float* __restrict__ maskB,   // B x Sk or null
    int Sq, int Sk, float inv_scale)
{
    __shared__ float sQ[16][64];
    __shared__ float sKV[64][65];
    __shared__ float sP[16][512];
    const int qt = blockIdx.x, h = blockIdx.y, b = blockIdx.z;
    const int tid = threadIdx.x;

    #pragma unroll
    for (int r = 0; r < 4; ++r) {
        int i = tid + r * 256;
        int q = i >> 6, d = i & 63;
        sQ[q][d] = Q[(size_t)(b * Sq + qt * 16 + q) * ldq + h * 64 + d];
    }
    __syncthreads();

    for (int t0 = 0; t0 < Sk; t0 += 64) {
        #pragma unroll
        for (int r = 0; r < 16; ++r) {
            int i = tid + r * 256;
            int t = i >> 6, d = i & 63;
            sKV[t][d] = Kb[(size_t)(b * Sk + t0 + t) * ldk + h * 64 + d];
        }
        __syncthreads();
        #pragma unroll
        for (int j = 0; j < 4; ++j) {
            int p = tid + 256 * j;
            int q = p >> 6, t = p & 63;
            float acc = 0.0f;
            #pragma unroll
            for (int d = 0; d < 64; ++d) acc = fmaf(sQ[q][d], sKV[t][d], acc);
            acc *= inv_scale;
            int tg = t0 + t;
            float mv = 0.0f;
            if (maskA) mv += maskA[(size_t)(qt * 16 + q) * Sk + tg];
            if (maskB) mv += maskB[(size_t)b * Sk + tg];
            bool masked = (mv < -1.0e30f) || (__float_as_uint(mv) == 0xFF800000u);
            sP[q][tg] = masked ? -3.0e38f : acc;
        }
        __syncthreads();
    }

    {
        int q = tid >> 4;
        int l = tid & 15;
        float mx = -3.0e38f;
        for (int t = l; t < Sk; t += 16) mx = fmaxf(mx, sP[q][t]);
        #pragma unroll
        for (int off = 8; off; off >>= 1) mx = fmaxf(mx, __shfl_xor(mx, off, 16));
        float sum = 0.0f;
        for (int t = l; t < Sk; t += 16) {
            float x = sP[q][t] - mx;
            float p = (x < -80.0f) ? 0.0f : __expf(x);
            sP[q][t] = p;
            sum += p;
        }
        #pragma unroll
        for (int off = 8; off; off >>= 1) sum += __shfl_xor(sum, off, 16);
        float inv = 1.0f / sum;
        for (int t = l; t < Sk; t += 16) sP[q][t] *= inv;
    }
    __syncthreads();

    float oacc[4] = {};
    const int d = tid & 63, qg = tid >> 6;
    for (int t0 = 0; t0 < Sk; t0 += 64) {
        #pragma unroll
        for (int r = 0; r < 16; ++r) {
            int i = tid + r * 256;
            int t = i >> 6, dd = i & 63;
            sKV[t][dd] = Vb[(size_t)(b * Sk + t0 + t) * ldv + h * 64 + dd];
        }
        __syncthreads();
        #pragma unroll 4
        for (int t = 0; t < 64; ++t) {
            float vv = sKV[t][d];
            #pragma unroll
            for (int j = 0; j < 4; ++j)
                oacc[j] = fmaf(sP[qg + 4 * j][t0 + t], vv, oacc[j]);
        }
        __syncthreads();
    }
    #pragma unroll
    for (int j = 0; j < 4; ++j) {
        int q = qg + 4 * j;
        O[(size_t)(b * Sq + qt * 16 + q) * ldo + h * 64 + d] = oacc[j];
    }
}

// ---------------- layernorm (in place, E=1024, one block per row) ------------
__global__ __launch_bounds__(256) void ln_kernel(float* __restrict__ X,
        const float* __restrict__ g, const float* __restrict__ bta) {
    __shared__ float wred[4];
    __shared__ float stat;
    float* x = X + ((size_t)blockIdx.x << 10);
    const int tid = threadIdx.x;
    float4 v = reinterpret_cast<float4*>(x)[tid];
    float s = v.x + v.y + v.z + v.w;
    #pragma unroll
    for (int off = 32; off; off >>= 1) s += __shfl_down(s, off, 64);
    if ((tid & 63) == 0) wred[tid >> 6] = s;
    __syncthreads();
    if (tid == 0) stat = (wred[0] + wred[1] + wred[2] + wred[3]) * (1.0f / 1024.0f);
    __syncthreads();
    float m = stat;
    float dx = v.x - m, dy = v.y - m, dz = v.z - m, dw = v.w - m;
    float s2 = dx * dx + dy * dy + dz * dz + dw * dw;
    #pragma unroll
    for (int off = 32; off; off >>= 1) s2 += __shfl_down(s2, off, 64);
    __syncthreads();
    if ((tid & 63) == 0) wred[tid >> 6] = s2;
    __syncthreads();
    if (tid == 0) stat = rsqrtf((wred[0] + wred[1] + wred[2] + wred[3]) * (1.0f / 1024.0f) + 1e-5f);
    __syncthreads();
    float r = stat;
    const float4 gv = reinterpret_cast<const float4*>(g)[tid];
    const float4 bv = reinterpret_cast<const float4*>(bta)[tid];
    float4 o;
    o.x = dx * r * gv.x + bv.x;
    o.y = dy * r * gv.y + bv.y;
    o.z = dz * r * gv.z + bv.z;
    o.w = dw * r * gv.w + bv.w;
    reinterpret_cast<float4*>(x)[tid] = o;
}

extern "C" void kernel_launch(void* const* d_in, const int* in_sizes, int n_in,
                              void* d_out, int out_size, void* d_ws, size_t ws_size,
                              hipStream_t stream) {
    const float* src      = (const float*)d_in[0];
    const float* tgt      = (const float*)d_in[1];
    const float* src_mask = (const float*)d_in[2];
    const float* tgt_mask = (const float*)d_in[3];
    const float* src_pad  = (const float*)d_in[4];
    const float* tgt_pad  = (const float*)d_in[5];
    const float* enc_wqkv = (const float*)d_in[6];
    const float* enc_wo   = (const float*)d_in[7];
    const float* enc_bo   = (const float*)d_in[8];
    const float* enc_w1   = (const float*)d_in[9];
    const float* enc_b1   = (const float*)d_in[10];
    const float* enc_w2   = (const float*)d_in[11];
    const float* enc_b2   = (const float*)d_in[12];
    const float* enc_lg   = (const float*)d_in[13];
    const float* enc_lb   = (const float*)d_in[14];
    const float* dq_s     = (const float*)d_in[15];
    const float* dwo_s    = (const float*)d_in[16];
    const float* dbo_s    = (const float*)d_in[17];
    const float* dq_c     = (const float*)d_in[18];
    const float* dwo_c    = (const float*)d_in[19];
    const float* dbo_c    = (const float*)d_in[20];
    const float* dw1      = (const float*)d_in[21];
    const float* db1      = (const float*)d_in[22];
    const float* dw2      = (const float*)d_in[23];
    const float* db2      = (const float*)d_in[24];
    const float* dlg      = (const float*)d_in[25];
    const float* dlb      = (const float*)d_in[26];

    float* xe  = (float*)d_ws;                      // 2048*1024
    float* y   = xe  + (size_t)NTOK * E_DIM;        // 2048*1024
    float* qkv = y   + (size_t)NTOK * E_DIM;        // 2048*3072
    float* att = qkv + (size_t)NTOK * 3 * E_DIM;    // 2048*1024
    float* ffh = qkv;   // FFN hidden aliases qkv+att (dead during FFN)

    const size_t WQKV_L = (size_t)3 * H_NUM * E_DIM * DH_DIM;
    const size_t HED    = (size_t)H_NUM * E_DIM * DH_DIM;
    const dim3 blk(256);

    // grids: (N/128, M/BM)
    const dim3 g_qkv(3072 / 128, NTOK / 128);     // 24 x 16
    const dim3 g_wo(1024 / 128, NTOK / 64);       // 8 x 32
    const dim3 g_ff1(4096 / 128, NTOK / 128);     // 32 x 16
    const dim3 g_ff2(1024 / 128, NTOK / 64);      // 8 x 32
    const dim3 g_attn(S_LEN / 16, H_NUM, B_SZ);

    transpose_in<<<(NTOK * E_DIM) / 256, blk, 0, stream>>>(src, xe);
    transpose_in<<<(NTOK * E_DIM) / 256, blk, 0, stream>>>(tgt, y);

    // -------- encoder --------
    for (int i = 0; i < 4; ++i) {
        gemm_mfma<128, true, false, false, false><<<g_qkv, blk, 0, stream>>>(
            xe, E_DIM, enc_wqkv + i * WQKV_L, 0, nullptr, nullptr, 0,
            qkv, 3072, NTOK, 3072, E_DIM);
        attn_kernel<<<g_attn, blk, 0, stream>>>(
            qkv, 3072, qkv + 1024, 3072, qkv + 2048, 3072, att, E_DIM,
            src_mask, src_pad, S_LEN, S_LEN, 0.125f);
        gemm_mfma<64, false, false, true, true><<<g_wo, blk, 0, stream>>>(
            att, E_DIM, enc_wo + (size_t)i * E_DIM * E_DIM, E_DIM, enc_bo + i * E_DIM,
            xe, E_DIM, xe, E_DIM, NTOK, E_DIM, E_DIM);
        ln_kernel<<<NTOK, blk, 0, stream>>>(xe, enc_lg + (size_t)(i * 2 + 0) * E_DIM,
                                            enc_lb + (size_t)(i * 2 + 0) * E_DIM);
        gemm_mfma<128, false, true, true, false><<<g_ff1, blk, 0, stream>>>(
            xe, E_DIM, enc_w1 + (size_t)i * E_DIM * DFF_DIM, DFF_DIM, enc_b1 + i * DFF_DIM,
            nullptr, 0, ffh, DFF_DIM, NTOK, DFF_DIM, E_DIM);
        gemm_mfma<64, false, false, true, true><<<g_ff2, blk, 0, stream>>>(
            ffh, DFF_DIM, enc_w2 + (size_t)i * DFF_DIM * E_DIM, E_DIM, enc_b2 + i * E_DIM,
            xe, E_DIM, xe, E_DIM, NTOK, E_DIM, DFF_DIM);
        ln_kernel<<<NTOK, blk, 0, stream>>>(xe, enc_lg + (size_t)(i * 2 + 1) * E_DIM,
                                            enc_lb + (size_t)(i * 2 + 1) * E_DIM);
    }

    // -------- decoder --------
    for (int i = 0; i < 4; ++i) {
        gemm_mfma<128, true, false, false, false><<<g_qkv, blk, 0, stream>>>(
            y, E_DIM, dq_s + i * WQKV_L, 0, nullptr, nullptr, 0,
            qkv, 3072, NTOK, 3072, E_DIM);
        attn_kernel<<<g_attn, blk, 0, stream>>>(
            qkv, 3072, qkv + 1024, 3072, qkv + 2048, 3072, att, E_DIM,
            tgt_mask, tgt_pad, S_LEN, S_LEN, 0.125f);
        gemm_mfma<64, false, false, true, true><<<g_wo, blk, 0, stream>>>(
            att, E_DIM, dwo_s + (size_t)i * E_DIM * E_DIM, E_DIM, dbo_s + i * E_DIM,
            y, E_DIM, y, E_DIM, NTOK, E_DIM, E_DIM);
        ln_kernel<<<NTOK, blk, 0, stream>>>(y, dlg + (size_t)(i * 3 + 0) * E_DIM,
                                            dlb + (size_t)(i * 3 + 0) * E_DIM);
        // cross-attention: q from y; k,v from encoder memory xe
        gemm_mfma<64, true, false, false, false><<<g_wo, blk, 0, stream>>>(
            y, E_DIM, dq_c + i * WQKV_L + 0 * HED, 0, nullptr, nullptr, 0,
            qkv, 3072, NTOK, E_DIM, E_DIM);
        gemm_mfma<64, true, false, false, false><<<g_wo, blk, 0, stream>>>(
            xe, E_DIM, dq_c + i * WQKV_L + 1 * HED, 0, nullptr, nullptr, 0,
            qkv + 1024, 3072, NTOK, E_DIM, E_DIM);
        gemm_mfma<64, true, false, false, false><<<g_wo, blk, 0, stream>>>(
            xe, E_DIM, dq_c + i * WQKV_L + 2 * HED, 0, nullptr, nullptr, 0,
            qkv + 2048, 3072, NTOK, E_DIM, E_DIM);
        attn_kernel<<<g_attn, blk, 0, stream>>>(
            qkv, 3072, qkv + 1024, 3072, qkv + 2048, 3072, att, E_DIM,
            nullptr, src_pad, S_LEN, S_LEN, 0.125f);
        gemm_mfma<64, false, false, true, true><<<g_wo, blk, 0, stream>>>(
            att, E_DIM, dwo_c + (size_t)i * E_DIM * E_DIM, E_DIM, dbo_c + i * E_DIM,
            y, E_DIM, y, E_DIM, NTOK, E_DIM, E_DIM);
        ln_kernel<<<NTOK, blk, 0, stream>>>(y, dlg + (size_t)(i * 3 + 1) * E_DIM,
                                            dlb + (size_t)(i * 3 + 1) * E_DIM);
        gemm_mfma<128, false, true, true, false><<<g_ff1, blk, 0, stream>>>(
            y, E_DIM, dw1 + (size_t)i * E_DIM * DFF_DIM, DFF_DIM, db1 + i * DFF_DIM,
            nullptr, 0, ffh, DFF_DIM, NTOK, DFF_DIM, E_DIM);
        gemm_mfma<64, false, false, true, true><<<g_ff2, blk, 0, stream>>>(
            ffh, DFF_DIM, dw2 + (size_t)i * DFF_DIM * E_DIM, E_DIM, db2 + i * E_DIM,
            y, E_DIM, y, E_DIM, NTOK, E_DIM, DFF_DIM);
        ln_kernel<<<NTOK, blk, 0, stream>>>(y, dlg + (size_t)(i * 3 + 2) * E_DIM,
                                            dlb + (size_t)(i * 3 + 2) * E_DIM);
    }

    writeout<<<(NTOK * E_DIM) / 256, blk, 0, stream>>>(y, (float*)d_out);
}

// Round 9
// 4395.214 us; speedup vs baseline: 2.3241x; 2.1972x over previous
//
#include <hip/hip_runtime.h>
#include <hip/hip_bf16.h>

typedef __hip_bfloat16 bf16;
typedef unsigned short u16;
typedef u16 u16x4 __attribute__((ext_vector_type(4)));
typedef u16 u16x8 __attribute__((ext_vector_type(8)));
typedef __bf16 bf16x8 __attribute__((ext_vector_type(8)));
typedef float f32x4 __attribute__((ext_vector_type(4)));

#define E_DIM 1024
#define DFF_DIM 4096
#define B_SZ 4
#define S_LEN 512
#define NTOK 2048

__device__ __forceinline__ u16 f2bf(float f) {           // RNE f32->bf16
    unsigned u = __float_as_uint(f);
    return (u16)((u + 0x7FFFu + ((u >> 16) & 1u)) >> 16);
}
__device__ __forceinline__ float bf2f(u16 x) {
    return __uint_as_float(((unsigned)x) << 16);
}
__device__ __forceinline__ void gload_lds16(const u16* g, u16* l) {
    __builtin_amdgcn_global_load_lds(
        (const __attribute__((address_space(1))) unsigned int*)g,
        (__attribute__((address_space(3))) unsigned int*)l, 16, 0, 0);
}

// ---------- transpose in: (S,B,E) f32 -> (B,S,E) f32 + bf16 ----------
__global__ __launch_bounds__(256) void transpose_in(const float* __restrict__ in,
                                                    float* __restrict__ out,
                                                    u16* __restrict__ outb) {
    size_t i = (size_t)blockIdx.x * 256 + threadIdx.x;
    int e = (int)(i & 1023);
    int sb = (int)(i >> 10);
    int b = sb & 3;
    int s = sb >> 2;
    float v = in[i];
    size_t o = ((size_t)((b << 9) + s) << 10) + e;
    out[o] = v;
    outb[o] = f2bf(v);
}

// ---------- writeout: (B,S,E) f32 -> (S,B,E) f32 ----------
__global__ __launch_bounds__(256) void writeout(const float* __restrict__ y,
                                                float* __restrict__ out) {
    size_t i = (size_t)blockIdx.x * 256 + threadIdx.x;
    int e = (int)(i & 1023);
    int sb = (int)(i >> 10);
    int b = sb & 3;
    int s = sb >> 2;
    out[i] = y[((size_t)((b << 9) + s) << 10) + e];
}

// ---------- weight transpose+cvt: W f32 [K][N] (or QKV blocked) -> Wt bf16 [N][K] ----
template<bool QKV>
__global__ __launch_bounds__(256) void cvt_wt(const float* __restrict__ W,
                                              u16* __restrict__ Wt, int K, int N) {
    __shared__ u16 ts[64][72];
    const int n0 = blockIdx.x * 64, k0 = blockIdx.y * 64;
    #pragma unroll
    for (int r = 0; r < 16; ++r) {
        int idx = threadIdx.x + r * 256;
        int k = idx >> 6, n = idx & 63;
        float v;
        if (QKV) v = W[(size_t)((n0 + n) >> 6) * ((size_t)K * 64) + (size_t)(k0 + k) * 64 + ((n0 + n) & 63)];
        else     v = W[(size_t)(k0 + k) * N + n0 + n];
        ts[n][k] = f2bf(v);
    }
    __syncthreads();
    #pragma unroll
    for (int r = 0; r < 2; ++r) {
        int idx = threadIdx.x + r * 256;
        int n = idx >> 3, c = idx & 7;
        u16x8 vv = *reinterpret_cast<const u16x8*>(&ts[n][c * 8]);
        *reinterpret_cast<u16x8*>(Wt + (size_t)(n0 + n) * K + k0 + c * 8) = vv;
    }
}

// ============ bf16 GEMM (m97 structure): C = A[M][K] @ Bt[N][K]^T ============
// EPI: 0 = bf16 out; 1 = bf16 out, bias+relu; 2 = f32 out, bias+residual
template<int BM, int EPI>
__global__ __launch_bounds__(256) void gemm_bt(
    const u16* __restrict__ A,
    const u16* __restrict__ Bt,
    const float* __restrict__ bias,
    const float* __restrict__ Res, int ldres,
    void* __restrict__ Cout, int ldc, int K)
{
    constexpr int MR = BM / 32;
    constexpr int AOPS = BM / 16;           // 1KB ops for A tile (BM x 32 bf16)
    __shared__ u16 As[BM * 32];
    __shared__ u16 Bs[128 * 32];
    const int tid = threadIdx.x;
    const int l = tid & 63, w = tid >> 6;
    const int m0 = blockIdx.y * BM, n0 = blockIdx.x * 128;
    const int mw = (w >> 1) * (BM / 2), nw = (w & 1) * 64;
    const int lr = l & 15, lg = l >> 4;
    const int srow = l >> 2, schunk = (l & 3) * 8;

    f32x4 acc[MR][4];
    #pragma unroll
    for (int mi = 0; mi < MR; ++mi)
        #pragma unroll
        for (int ni = 0; ni < 4; ++ni) acc[mi][ni] = (f32x4)(0.0f);

    const u16* ap = A + (size_t)(m0 + srow) * K + schunk;
    const u16* bp = Bt + (size_t)(n0 + srow) * K + schunk;

    for (int k0 = 0; k0 < K; k0 += 32) {
        #pragma unroll
        for (int op = w; op < AOPS; op += 4)
            gload_lds16(ap + (size_t)op * 16 * K + k0, As + op * 512);
        #pragma unroll
        for (int op = w; op < 8; op += 4)
            gload_lds16(bp + (size_t)op * 16 * K + k0, Bs + op * 512);
        __syncthreads();

        u16x8 af[MR], bfr[4];
        #pragma unroll
        for (int mi = 0; mi < MR; ++mi)
            af[mi] = *reinterpret_cast<const u16x8*>(&As[(mw + mi * 16 + lr) * 32 + lg * 8]);
        #pragma unroll
        for (int ni = 0; ni < 4; ++ni)
            bfr[ni] = *reinterpret_cast<const u16x8*>(&Bs[(nw + ni * 16 + lr) * 32 + lg * 8]);
        #pragma unroll
        for (int mi = 0; mi < MR; ++mi)
            #pragma unroll
            for (int ni = 0; ni < 4; ++ni)
                acc[mi][ni] = __builtin_amdgcn_mfma_f32_16x16x32_bf16(
                    __builtin_bit_cast(bf16x8, af[mi]),
                    __builtin_bit_cast(bf16x8, bfr[ni]),
                    acc[mi][ni], 0, 0, 0);
        __syncthreads();
    }

    // epilogue: C/D frag col = lane&15, row = (lane>>4)*4 + reg
    #pragma unroll
    for (int mi = 0; mi < MR; ++mi) {
        #pragma unroll
        for (int ni = 0; ni < 4; ++ni) {
            const int gc = n0 + nw + ni * 16 + lr;
            float bv = 0.0f;
            if constexpr (EPI >= 1) bv = bias[gc];
            #pragma unroll
            for (int r = 0; r < 4; ++r) {
                const int gr = m0 + mw + mi * 16 + lg * 4 + r;
                float v = acc[mi][ni][r] + bv;
                if constexpr (EPI == 1) v = fmaxf(v, 0.0f);
                if constexpr (EPI == 2) {
                    ((float*)Cout)[(size_t)gr * ldc + gc] = v + Res[(size_t)gr * ldres + gc];
                } else {
                    ((u16*)Cout)[(size_t)gr * ldc + gc] = f2bf(v);
                }
            }
        }
    }
}

// ---------- attention (bf16 in/out, f32 math): per-(b,h,16-query tile) ----------
__global__ __launch_bounds__(256) void attn_kernel(
    const u16* __restrict__ Qb, const u16* __restrict__ Kb, const u16* __restrict__ Vb,
    int ldqkv, u16* __restrict__ Ob, int ldo,
    const float* __restrict__ maskA, const float* __restrict__ maskB,
    int Sq, int Sk, float inv_scale)
{
    __shared__ float sQ[16][64];
    __shared__ float sKV[64][65];
    __shared__ float sP[16][512];
    const int qt = blockIdx.x, h = blockIdx.y, b = blockIdx.z;
    const int tid = threadIdx.x;

    #pragma unroll
    for (int r = 0; r < 4; ++r) {
        int i = tid + r * 256;
        int q = i >> 6, d = i & 63;
        sQ[q][d] = bf2f(Qb[(size_t)(b * Sq + qt * 16 + q) * ldqkv + h * 64 + d]);
    }
    __syncthreads();

    for (int t0 = 0; t0 < Sk; t0 += 64) {
        #pragma unroll
        for (int r = 0; r < 16; ++r) {
            int i = tid + r * 256;
            int t = i >> 6, d = i & 63;
            sKV[t][d] = bf2f(Kb[(size_t)(b * Sk + t0 + t) * ldqkv + h * 64 + d]);
        }
        __syncthreads();
        #pragma unroll
        for (int j = 0; j < 4; ++j) {
            int p = tid + 256 * j;
            int q = p >> 6, t = p & 63;
            float acc = 0.0f;
            #pragma unroll
            for (int d = 0; d < 64; ++d) acc = fmaf(sQ[q][d], sKV[t][d], acc);
            acc *= inv_scale;
            int tg = t0 + t;
            float mv = 0.0f;
            if (maskA) mv += maskA[(size_t)(qt * 16 + q) * Sk + tg];
            if (maskB) mv += maskB[(size_t)b * Sk + tg];
            bool masked = (mv < -1.0e30f) || (__float_as_uint(mv) == 0xFF800000u);
            sP[q][tg] = masked ? -3.0e38f : acc;
        }
        __syncthreads();
    }

    {
        int q = tid >> 4;
        int l = tid & 15;
        float mx = -3.0e38f;
        for (int t = l; t < Sk; t += 16) mx = fmaxf(mx, sP[q][t]);
        #pragma unroll
        for (int off = 8; off; off >>= 1) mx = fmaxf(mx, __shfl_xor(mx, off, 16));
        float sum = 0.0f;
        for (int t = l; t < Sk; t += 16) {
            float x = sP[q][t] - mx;
            float p = (x < -80.0f) ? 0.0f : __expf(x);
            sP[q][t] = p;
            sum += p;
        }
        #pragma unroll
        for (int off = 8; off; off >>= 1) sum += __shfl_xor(sum, off, 16);
        float inv = 1.0f / sum;
        for (int t = l; t < Sk; t += 16) sP[q][t] *= inv;
    }
    __syncthreads();

    float oacc[4] = {};
    const int d = tid & 63, qg = tid >> 6;
    for (int t0 = 0; t0 < Sk; t0 += 64) {
        #pragma unroll
        for (int r = 0; r < 16; ++r) {
            int i = tid + r * 256;
            int t = i >> 6, dd = i & 63;
            sKV[t][dd] = bf2f(Vb[(size_t)(b * Sk + t0 + t) * ldqkv + h * 64 + dd]);
        }
        __syncthreads();
        #pragma unroll 4
        for (int t = 0; t < 64; ++t) {
            float vv = sKV[t][d];
            #pragma unroll
            for (int j = 0; j < 4; ++j)
                oacc[j] = fmaf(sP[qg + 4 * j][t0 + t], vv, oacc[j]);
        }
        __syncthreads();
    }
    #pragma unroll
    for (int j = 0; j < 4; ++j) {
        int q = qg + 4 * j;
        Ob[(size_t)(b * Sq + qt * 16 + q) * ldo + h * 64 + d] = f2bf(oacc[j]);
    }
}

// ---------- layernorm: in-place f32 + bf16 copy ----------
__global__ __launch_bounds__(256) void ln_kernel(float* __restrict__ X,
        const float* __restrict__ g, const float* __restrict__ bta,
        u16* __restrict__ outb) {
    __shared__ float wred[4];
    __shared__ float stat;
    float* x = X + ((size_t)blockIdx.x << 10);
    const int tid = threadIdx.x;
    float4 v = reinterpret_cast<float4*>(x)[tid];
    float s = v.x + v.y + v.z + v.w;
    #pragma unroll
    for (int off = 32; off; off >>= 1) s += __shfl_down(s, off, 64);
    if ((tid & 63) == 0) wred[tid >> 6] = s;
    __syncthreads();
    if (tid == 0) stat = (wred[0] + wred[1] + wred[2] + wred[3]) * (1.0f / 1024.0f);
    __syncthreads();
    float m = stat;
    float dx = v.x - m, dy = v.y - m, dz = v.z - m, dw = v.w - m;
    float s2 = dx * dx + dy * dy + dz * dz + dw * dw;
    #pragma unroll
    for (int off = 32; off; off >>= 1) s2 += __shfl_down(s2, off, 64);
    __syncthreads();
    if ((tid & 63) == 0) wred[tid >> 6] = s2;
    __syncthreads();
    if (tid == 0) stat = rsqrtf((wred[0] + wred[1] + wred[2] + wred[3]) * (1.0f / 1024.0f) + 1e-5f);
    __syncthreads();
    float r = stat;
    const float4 gv = reinterpret_cast<const float4*>(g)[tid];
    const float4 bv = reinterpret_cast<const float4*>(bta)[tid];
    float4 o;
    o.x = dx * r * gv.x + bv.x;
    o.y = dy * r * gv.y + bv.y;
    o.z = dz * r * gv.z + bv.z;
    o.w = dw * r * gv.w + bv.w;
    reinterpret_cast<float4*>(x)[tid] = o;
    u16x4 ob;
    ob.x = f2bf(o.x); ob.y = f2bf(o.y); ob.z = f2bf(o.z); ob.w = f2bf(o.w);
    *reinterpret_cast<u16x4*>(outb + ((size_t)blockIdx.x << 10) + (tid << 2)) = ob;
}

extern "C" void kernel_launch(void* const* d_in, const int* in_sizes, int n_in,
                              void* d_out, int out_size, void* d_ws, size_t ws_size,
                              hipStream_t stream) {
    const float* src      = (const float*)d_in[0];
    const float* tgt      = (const float*)d_in[1];
    const float* src_mask = (const float*)d_in[2];
    const float* tgt_mask = (const float*)d_in[3];
    const float* src_pad  = (const float*)d_in[4];
    const float* tgt_pad  = (const float*)d_in[5];
    const float* enc_wqkv = (const float*)d_in[6];
    const float* enc_wo   = (const float*)d_in[7];
    const float* enc_bo   = (const float*)d_in[8];
    const float* enc_w1   = (const float*)d_in[9];
    const float* enc_b1   = (const float*)d_in[10];
    const float* enc_w2   = (const float*)d_in[11];
    const float* enc_b2   = (const float*)d_in[12];
    const float* enc_lg   = (const float*)d_in[13];
    const float* enc_lb   = (const float*)d_in[14];
    const float* dq_s     = (const float*)d_in[15];
    const float* dwo_s    = (const float*)d_in[16];
    const float* dbo_s    = (const float*)d_in[17];
    const float* dq_c     = (const float*)d_in[18];
    const float* dwo_c    = (const float*)d_in[19];
    const float* dbo_c    = (const float*)d_in[20];
    const float* dw1      = (const float*)d_in[21];
    const float* db1      = (const float*)d_in[22];
    const float* dw2      = (const float*)d_in[23];
    const float* db2      = (const float*)d_in[24];
    const float* dlg      = (const float*)d_in[25];
    const float* dlb      = (const float*)d_in[26];

    // ---- workspace: exactly 48 MiB (probe-verified available) ----
    float* xe = (float*)d_ws;                    // 2M f32
    float* y  = xe + (size_t)NTOK * E_DIM;       // 2M f32
    u16* xeb  = (u16*)(y + (size_t)NTOK * E_DIM);
    u16* yb   = xeb  + (size_t)NTOK * E_DIM;     // 2M
    u16* qkvb = yb   + (size_t)NTOK * E_DIM;     // 6M
    u16* attb = qkvb + (size_t)NTOK * 3 * E_DIM; // 2M
    u16* ffhb = qkvb;                            // alias 8M (qkvb+attb)
    u16* wt   = attb + (size_t)NTOK * E_DIM;     // 4M u16 = 8 MiB

    const size_t WQKV_L = (size_t)3 * 16 * E_DIM * 64;
    const dim3 blk(256);
    const dim3 g_attn(S_LEN / 16, 16, B_SZ);
    const dim3 g_qkv(3072 / 128, NTOK / 128);
    const dim3 g_kv(2048 / 128, NTOK / 64);
    const dim3 g_e(1024 / 128, NTOK / 64);
    const dim3 g_ff1(4096 / 128, NTOK / 128);
    const dim3 c_qkv(3072 / 64, 1024 / 64);
    const dim3 c_e(1024 / 64, 1024 / 64);
    const dim3 c_w1(4096 / 64, 1024 / 64);
    const dim3 c_w2(1024 / 64, 4096 / 64);

    transpose_in<<<(NTOK * E_DIM) / 256, blk, 0, stream>>>(src, xe, xeb);
    transpose_in<<<(NTOK * E_DIM) / 256, blk, 0, stream>>>(tgt, y, yb);

    // -------- encoder --------
    for (int i = 0; i < 4; ++i) {
        cvt_wt<true><<<c_qkv, blk, 0, stream>>>(enc_wqkv + i * WQKV_L, wt, 1024, 3072);
        gemm_bt<128, 0><<<g_qkv, blk, 0, stream>>>(xeb, wt, nullptr, nullptr, 0, qkvb, 3072, 1024);
        attn_kernel<<<g_attn, blk, 0, stream>>>(qkvb, qkvb + 1024, qkvb + 2048, 3072,
                                                attb, 1024, src_mask, src_pad, S_LEN, S_LEN, 0.125f);
        cvt_wt<false><<<c_e, blk, 0, stream>>>(enc_wo + (size_t)i * E_DIM * E_DIM, wt, 1024, 1024);
        gemm_bt<64, 2><<<g_e, blk, 0, stream>>>(attb, wt, enc_bo + i * E_DIM, xe, 1024, xe, 1024, 1024);
        ln_kernel<<<NTOK, blk, 0, stream>>>(xe, enc_lg + (size_t)(i * 2 + 0) * E_DIM,
                                            enc_lb + (size_t)(i * 2 + 0) * E_DIM, xeb);
        cvt_wt<false><<<c_w1, blk, 0, stream>>>(enc_w1 + (size_t)i * E_DIM * DFF_DIM, wt, 1024, 4096);
        gemm_bt<128, 1><<<g_ff1, blk, 0, stream>>>(xeb, wt, enc_b1 + i * DFF_DIM, nullptr, 0, ffhb, 4096, 1024);
        cvt_wt<false><<<c_w2, blk, 0, stream>>>(enc_w2 + (size_t)i * DFF_DIM * E_DIM, wt, 4096, 1024);
        gemm_bt<64, 2><<<g_e, blk, 0, stream>>>(ffhb, wt, enc_b2 + i * E_DIM, xe, 1024, xe, 1024, 4096);
        ln_kernel<<<NTOK, blk, 0, stream>>>(xe, enc_lg + (size_t)(i * 2 + 1) * E_DIM,
                                            enc_lb + (size_t)(i * 2 + 1) * E_DIM, xeb);
    }

    // -------- decoder --------
    for (int i = 0; i < 4; ++i) {
        cvt_wt<true><<<c_qkv, blk, 0, stream>>>(dq_s + i * WQKV_L, wt, 1024, 3072);
        gemm_bt<128, 0><<<g_qkv, blk, 0, stream>>>(yb, wt, nullptr, nullptr, 0, qkvb, 3072, 1024);
        attn_kernel<<<g_attn, blk, 0, stream>>>(qkvb, qkvb + 1024, qkvb + 2048, 3072,
                                                attb, 1024, tgt_mask, tgt_pad, S_LEN, S_LEN, 0.125f);
        cvt_wt<false><<<c_e, blk, 0, stream>>>(dwo_s + (size_t)i * E_DIM * E_DIM, wt, 1024, 1024);
        gemm_bt<64, 2><<<g_e, blk, 0, stream>>>(attb, wt, dbo_s + i * E_DIM, y, 1024, y, 1024, 1024);
        ln_kernel<<<NTOK, blk, 0, stream>>>(y, dlg + (size_t)(i * 3 + 0) * E_DIM,
                                            dlb + (size_t)(i * 3 + 0) * E_DIM, yb);
        // cross-attention
        cvt_wt<true><<<c_qkv, blk, 0, stream>>>(dq_c + i * WQKV_L, wt, 1024, 3072);
        gemm_bt<64, 0><<<g_e, blk, 0, stream>>>(yb, wt, nullptr, nullptr, 0, qkvb, 3072, 1024);
        gemm_bt<64, 0><<<g_kv, blk, 0, stream>>>(xeb, wt + (size_t)1024 * 1024, nullptr, nullptr, 0,
                                                 qkvb + 1024, 3072, 1024);
        attn_kernel<<<g_attn, blk, 0, stream>>>(qkvb, qkvb + 1024, qkvb + 2048, 3072,
                                                attb, 1024, nullptr, src_pad, S_LEN, S_LEN, 0.125f);
        cvt_wt<false><<<c_e, blk, 0, stream>>>(dwo_c + (size_t)i * E_DIM * E_DIM, wt, 1024, 1024);
        gemm_bt<64, 2><<<g_e, blk, 0, stream>>>(attb, wt, dbo_c + i * E_DIM, y, 1024, y, 1024, 1024);
        ln_kernel<<<NTOK, blk, 0, stream>>>(y, dlg + (size_t)(i * 3 + 1) * E_DIM,
                                            dlb + (size_t)(i * 3 + 1) * E_DIM, yb);
        // FFN
        cvt_wt<false><<<c_w1, blk, 0, stream>>>(dw1 + (size_t)i * E_DIM * DFF_DIM, wt, 1024, 4096);
        gemm_bt<128, 1><<<g_ff1, blk, 0, stream>>>(yb, wt, db1 + i * DFF_DIM, nullptr, 0, ffhb, 4096, 1024);
        cvt_wt<false><<<c_w2, blk, 0, stream>>>(dw2 + (size_t)i * DFF_DIM * E_DIM, wt, 4096, 1024);
        gemm_bt<64, 2><<<g_e, blk, 0, stream>>>(ffhb, wt, db2 + i * E_DIM, y, 1024, y, 1024, 4096);
        ln_kernel<<<NTOK, blk, 0, stream>>>(y, dlg + (size_t)(i * 3 + 2) * E_DIM,
                                            dlb + (size_t)(i * 3 + 2) * E_DIM, yb);
    }

    writeout<<<(NTOK * E_DIM) / 256, blk, 0, stream>>>(y, (float*)d_out);
}

// Round 10
// 2435.335 us; speedup vs baseline: 4.1945x; 1.8048x over previous
//
#include <hip/hip_runtime.h>
#include <hip/hip_bf16.h>

typedef __hip_bfloat16 bf16;
typedef unsigned short u16;
typedef u16 u16x4 __attribute__((ext_vector_type(4)));
typedef u16 u16x8 __attribute__((ext_vector_type(8)));
typedef __bf16 bf16x8 __attribute__((ext_vector_type(8)));
typedef float f32x4 __attribute__((ext_vector_type(4)));

#define E_DIM 1024
#define DFF_DIM 4096
#define B_SZ 4
#define S_LEN 512
#define NTOK 2048

__device__ __forceinline__ u16 f2bf(float f) {           // RNE f32->bf16
    unsigned u = __float_as_uint(f);
    return (u16)((u + 0x7FFFu + ((u >> 16) & 1u)) >> 16);
}
__device__ __forceinline__ float bf2f(u16 x) {
    return __uint_as_float(((unsigned)x) << 16);
}
__device__ __forceinline__ void gload_lds16(const u16* g, u16* l) {
    __builtin_amdgcn_global_load_lds(
        (const __attribute__((address_space(1))) unsigned int*)g,
        (__attribute__((address_space(3))) unsigned int*)l, 16, 0, 0);
}

// ---------- transpose in: (S,B,E) f32 -> (B,S,E) f32 + bf16 ----------
__global__ __launch_bounds__(256) void transpose_in(const float* __restrict__ in,
                                                    float* __restrict__ out,
                                                    u16* __restrict__ outb) {
    size_t i = (size_t)blockIdx.x * 256 + threadIdx.x;
    int e = (int)(i & 1023);
    int sb = (int)(i >> 10);
    int b = sb & 3;
    int s = sb >> 2;
    float v = in[i];
    size_t o = ((size_t)((b << 9) + s) << 10) + e;
    out[o] = v;
    outb[o] = f2bf(v);
}

// ---------- writeout: (B,S,E) f32 -> (S,B,E) f32 ----------
__global__ __launch_bounds__(256) void writeout(const float* __restrict__ y,
                                                float* __restrict__ out) {
    size_t i = (size_t)blockIdx.x * 256 + threadIdx.x;
    int e = (int)(i & 1023);
    int sb = (int)(i >> 10);
    int b = sb & 3;
    int s = sb >> 2;
    out[i] = y[((size_t)((b << 9) + s) << 10) + e];
}

// ---------- weight transpose+cvt: W f32 [K][N] (or QKV blocked) -> Wt bf16 [N][K] ----
template<bool QKV>
__global__ __launch_bounds__(256) void cvt_wt(const float* __restrict__ W,
                                              u16* __restrict__ Wt, int K, int N) {
    __shared__ u16 ts[64][72];
    const int n0 = blockIdx.x * 64, k0 = blockIdx.y * 64;
    #pragma unroll
    for (int r = 0; r < 16; ++r) {
        int idx = threadIdx.x + r * 256;
        int k = idx >> 6, n = idx & 63;
        float v;
        if (QKV) v = W[(size_t)((n0 + n) >> 6) * ((size_t)K * 64) + (size_t)(k0 + k) * 64 + ((n0 + n) & 63)];
        else     v = W[(size_t)(k0 + k) * N + n0 + n];
        ts[n][k] = f2bf(v);
    }
    __syncthreads();
    #pragma unroll
    for (int r = 0; r < 2; ++r) {
        int idx = threadIdx.x + r * 256;
        int n = idx >> 3, c = idx & 7;
        u16x8 vv = *reinterpret_cast<const u16x8*>(&ts[n][c * 8]);
        *reinterpret_cast<u16x8*>(Wt + (size_t)(n0 + n) * K + k0 + c * 8) = vv;
    }
}

// ============ bf16 GEMM (m97 structure): C = A[M][K] @ Bt[N][K]^T ============
// EPI: 0 = bf16 out; 1 = bf16 out, bias+relu; 2 = f32 out, bias+residual
template<int BM, int EPI>
__global__ __launch_bounds__(256) void gemm_bt(
    const u16* __restrict__ A,
    const u16* __restrict__ Bt,
    const float* __restrict__ bias,
    const float* __restrict__ Res, int ldres,
    void* __restrict__ Cout, int ldc, int K)
{
    constexpr int MR = BM / 32;
    constexpr int AOPS = BM / 16;
    __shared__ u16 As[BM * 32];
    __shared__ u16 Bs[128 * 32];
    const int tid = threadIdx.x;
    const int l = tid & 63, w = tid >> 6;
    const int m0 = blockIdx.y * BM, n0 = blockIdx.x * 128;
    const int mw = (w >> 1) * (BM / 2), nw = (w & 1) * 64;
    const int lr = l & 15, lg = l >> 4;
    const int srow = l >> 2, schunk = (l & 3) * 8;

    f32x4 acc[MR][4];
    #pragma unroll
    for (int mi = 0; mi < MR; ++mi)
        #pragma unroll
        for (int ni = 0; ni < 4; ++ni) acc[mi][ni] = (f32x4)(0.0f);

    const u16* ap = A + (size_t)(m0 + srow) * K + schunk;
    const u16* bp = Bt + (size_t)(n0 + srow) * K + schunk;

    for (int k0 = 0; k0 < K; k0 += 32) {
        #pragma unroll
        for (int op = w; op < AOPS; op += 4)
            gload_lds16(ap + (size_t)op * 16 * K + k0, As + op * 512);
        #pragma unroll
        for (int op = w; op < 8; op += 4)
            gload_lds16(bp + (size_t)op * 16 * K + k0, Bs + op * 512);
        __syncthreads();

        u16x8 af[MR], bfr[4];
        #pragma unroll
        for (int mi = 0; mi < MR; ++mi)
            af[mi] = *reinterpret_cast<const u16x8*>(&As[(mw + mi * 16 + lr) * 32 + lg * 8]);
        #pragma unroll
        for (int ni = 0; ni < 4; ++ni)
            bfr[ni] = *reinterpret_cast<const u16x8*>(&Bs[(nw + ni * 16 + lr) * 32 + lg * 8]);
        #pragma unroll
        for (int mi = 0; mi < MR; ++mi)
            #pragma unroll
            for (int ni = 0; ni < 4; ++ni)
                acc[mi][ni] = __builtin_amdgcn_mfma_f32_16x16x32_bf16(
                    __builtin_bit_cast(bf16x8, af[mi]),
                    __builtin_bit_cast(bf16x8, bfr[ni]),
                    acc[mi][ni], 0, 0, 0);
        __syncthreads();
    }

    #pragma unroll
    for (int mi = 0; mi < MR; ++mi) {
        #pragma unroll
        for (int ni = 0; ni < 4; ++ni) {
            const int gc = n0 + nw + ni * 16 + lr;
            float bv = 0.0f;
            if constexpr (EPI >= 1) bv = bias[gc];
            #pragma unroll
            for (int r = 0; r < 4; ++r) {
                const int gr = m0 + mw + mi * 16 + lg * 4 + r;
                float v = acc[mi][ni][r] + bv;
                if constexpr (EPI == 1) v = fmaxf(v, 0.0f);
                if constexpr (EPI == 2) {
                    ((float*)Cout)[(size_t)gr * ldc + gc] = v + Res[(size_t)gr * ldres + gc];
                } else {
                    ((u16*)Cout)[(size_t)gr * ldc + gc] = f2bf(v);
                }
            }
        }
    }
}

// ---------- V transpose: qkv V [b][t][h*64+d] -> Vt [(b*16+h)*64+d][t] ----------
__global__ __launch_bounds__(256) void vt_gen(const u16* __restrict__ V,
                                              u16* __restrict__ Vt) {
    __shared__ u16 ts[64][72];
    const int bh = blockIdx.y, b = bh >> 4, h = bh & 15;
    const int t0 = blockIdx.x * 64;
    #pragma unroll
    for (int r = 0; r < 2; ++r) {
        int idx = threadIdx.x + r * 256;
        int t = idx >> 3, c = idx & 7;
        u16x8 v = *reinterpret_cast<const u16x8*>(
            V + (size_t)(b * 512 + t0 + t) * 3072 + h * 64 + c * 8);
        *reinterpret_cast<u16x8*>(&ts[t][c * 8]) = v;
    }
    __syncthreads();
    #pragma unroll
    for (int r = 0; r < 2; ++r) {
        int idx = threadIdx.x + r * 256;
        int d = idx >> 3, tc = idx & 7;
        u16x8 o;
        #pragma unroll
        for (int j = 0; j < 8; ++j) o[j] = ts[tc * 8 + j][d];
        *reinterpret_cast<u16x8*>(Vt + ((size_t)(bh * 64 + d)) * 512 + t0 + tc * 8) = o;
    }
}

// ============ MFMA attention: block = (qt, h, b), 16 queries, 4 waves ============
// Qb/Kb: [token][3072] bf16 (ld 3072); Vt: [(b*16+h)*64+d][512] bf16
template<bool HAS_MA>
__global__ __launch_bounds__(256) void attn_mfma(
    const u16* __restrict__ Qb, const u16* __restrict__ Kb,
    const u16* __restrict__ Vt, u16* __restrict__ Ob,
    const float* __restrict__ maskA, const float* __restrict__ maskB,
    float inv_scale)
{
    __shared__ float sS[16][520];
    __shared__ u16 sP[16][520];
    const int qt = blockIdx.x, h = blockIdx.y, b = blockIdx.z;
    const int tid = threadIdx.x;
    const int l = tid & 63, w = tid >> 6;
    const int lr = l & 15, lg = l >> 4;

    // ---- phase 1: scores = Q @ K^T (wave w owns t-strip w*128..+128) ----
    const u16* qbase = Qb + (size_t)(b * 512 + qt * 16 + lr) * 3072 + h * 64 + lg * 8;
    u16x8 qf0 = *reinterpret_cast<const u16x8*>(qbase);
    u16x8 qf1 = *reinterpret_cast<const u16x8*>(qbase + 32);

    f32x4 sacc[8];
    #pragma unroll
    for (int ni = 0; ni < 8; ++ni) sacc[ni] = (f32x4)(0.0f);
    #pragma unroll
    for (int ni = 0; ni < 8; ++ni) {
        const int t0 = w * 128 + ni * 16;
        const u16* kbase = Kb + (size_t)(b * 512 + t0 + lr) * 3072 + h * 64 + lg * 8;
        u16x8 kf0 = *reinterpret_cast<const u16x8*>(kbase);
        u16x8 kf1 = *reinterpret_cast<const u16x8*>(kbase + 32);
        sacc[ni] = __builtin_amdgcn_mfma_f32_16x16x32_bf16(
            __builtin_bit_cast(bf16x8, qf0), __builtin_bit_cast(bf16x8, kf0), sacc[ni], 0, 0, 0);
        sacc[ni] = __builtin_amdgcn_mfma_f32_16x16x32_bf16(
            __builtin_bit_cast(bf16x8, qf1), __builtin_bit_cast(bf16x8, kf1), sacc[ni], 0, 0, 0);
    }
    #pragma unroll
    for (int ni = 0; ni < 8; ++ni)
        #pragma unroll
        for (int r = 0; r < 4; ++r)
            sS[lg * 4 + r][w * 128 + ni * 16 + lr] = sacc[ni][r] * inv_scale;
    __syncthreads();

    // ---- phase 2: masked softmax, P -> bf16 ----
    {
        const int q = tid >> 4, ll = tid & 15;
        const float* mArow = HAS_MA ? maskA + (size_t)(qt * 16 + q) * 512 : nullptr;
        const float* mBrow = maskB + (size_t)b * 512;
        float mx = -3.0e38f;
        for (int t = ll; t < 512; t += 16) {
            float mv = mBrow[t];
            if (HAS_MA) mv += mArow[t];
            bool masked = (mv < -1.0e30f) || (__float_as_uint(mv) == 0xFF800000u);
            float v = masked ? -3.0e38f : sS[q][t];
            sS[q][t] = v;
            mx = fmaxf(mx, v);
        }
        #pragma unroll
        for (int off = 8; off; off >>= 1) mx = fmaxf(mx, __shfl_xor(mx, off, 16));
        float sum = 0.0f;
        for (int t = ll; t < 512; t += 16) {
            float x = sS[q][t] - mx;
            float p = (x < -80.0f) ? 0.0f : __expf(x);
            sS[q][t] = p;
            sum += p;
        }
        #pragma unroll
        for (int off = 8; off; off >>= 1) sum += __shfl_xor(sum, off, 16);
        const float inv = 1.0f / sum;
        for (int t = ll; t < 512; t += 16) sP[q][t] = f2bf(sS[q][t] * inv);
    }
    __syncthreads();

    // ---- phase 3: O = P @ V (wave w owns d-tile w*16..+16) ----
    const u16* vbase = Vt + ((size_t)((b * 16 + h) * 64 + w * 16 + lr)) * 512 + lg * 8;
    f32x4 oa = (f32x4)(0.0f);
    #pragma unroll
    for (int kt = 0; kt < 16; ++kt) {
        u16x8 pf = *reinterpret_cast<const u16x8*>(&sP[lr][kt * 32 + lg * 8]);
        u16x8 vf = *reinterpret_cast<const u16x8*>(vbase + kt * 32);
        oa = __builtin_amdgcn_mfma_f32_16x16x32_bf16(
            __builtin_bit_cast(bf16x8, pf), __builtin_bit_cast(bf16x8, vf), oa, 0, 0, 0);
    }
    #pragma unroll
    for (int r = 0; r < 4; ++r)
        Ob[(size_t)(b * 512 + qt * 16 + lg * 4 + r) * 1024 + h * 64 + w * 16 + lr] = f2bf(oa[r]);
}

// ---------- layernorm: in-place f32 + bf16 copy ----------
__global__ __launch_bounds__(256) void ln_kernel(float* __restrict__ X,
        const float* __restrict__ g, const float* __restrict__ bta,
        u16* __restrict__ outb) {
    __shared__ float wred[4];
    __shared__ float stat;
    float* x = X + ((size_t)blockIdx.x << 10);
    const int tid = threadIdx.x;
    float4 v = reinterpret_cast<float4*>(x)[tid];
    float s = v.x + v.y + v.z + v.w;
    #pragma unroll
    for (int off = 32; off; off >>= 1) s += __shfl_down(s, off, 64);
    if ((tid & 63) == 0) wred[tid >> 6] = s;
    __syncthreads();
    if (tid == 0) stat = (wred[0] + wred[1] + wred[2] + wred[3]) * (1.0f / 1024.0f);
    __syncthreads();
    float m = stat;
    float dx = v.x - m, dy = v.y - m, dz = v.z - m, dw = v.w - m;
    float s2 = dx * dx + dy * dy + dz * dz + dw * dw;
    #pragma unroll
    for (int off = 32; off; off >>= 1) s2 += __shfl_down(s2, off, 64);
    __syncthreads();
    if ((tid & 63) == 0) wred[tid >> 6] = s2;
    __syncthreads();
    if (tid == 0) stat = rsqrtf((wred[0] + wred[1] + wred[2] + wred[3]) * (1.0f / 1024.0f) + 1e-5f);
    __syncthreads();
    float r = stat;
    const float4 gv = reinterpret_cast<const float4*>(g)[tid];
    const float4 bv = reinterpret_cast<const float4*>(bta)[tid];
    float4 o;
    o.x = dx * r * gv.x + bv.x;
    o.y = dy * r * gv.y + bv.y;
    o.z = dz * r * gv.z + bv.z;
    o.w = dw * r * gv.w + bv.w;
    reinterpret_cast<float4*>(x)[tid] = o;
    u16x4 ob;
    ob.x = f2bf(o.x); ob.y = f2bf(o.y); ob.z = f2bf(o.z); ob.w = f2bf(o.w);
    *reinterpret_cast<u16x4*>(outb + ((size_t)blockIdx.x << 10) + (tid << 2)) = ob;
}

extern "C" void kernel_launch(void* const* d_in, const int* in_sizes, int n_in,
                              void* d_out, int out_size, void* d_ws, size_t ws_size,
                              hipStream_t stream) {
    const float* src      = (const float*)d_in[0];
    const float* tgt      = (const float*)d_in[1];
    const float* src_mask = (const float*)d_in[2];
    const float* tgt_mask = (const float*)d_in[3];
    const float* src_pad  = (const float*)d_in[4];
    const float* tgt_pad  = (const float*)d_in[5];
    const float* enc_wqkv = (const float*)d_in[6];
    const float* enc_wo   = (const float*)d_in[7];
    const float* enc_bo   = (const float*)d_in[8];
    const float* enc_w1   = (const float*)d_in[9];
    const float* enc_b1   = (const float*)d_in[10];
    const float* enc_w2   = (const float*)d_in[11];
    const float* enc_b2   = (const float*)d_in[12];
    const float* enc_lg   = (const float*)d_in[13];
    const float* enc_lb   = (const float*)d_in[14];
    const float* dq_s     = (const float*)d_in[15];
    const float* dwo_s    = (const float*)d_in[16];
    const float* dbo_s    = (const float*)d_in[17];
    const float* dq_c     = (const float*)d_in[18];
    const float* dwo_c    = (const float*)d_in[19];
    const float* dbo_c    = (const float*)d_in[20];
    const float* dw1      = (const float*)d_in[21];
    const float* db1      = (const float*)d_in[22];
    const float* dw2      = (const float*)d_in[23];
    const float* db2      = (const float*)d_in[24];
    const float* dlg      = (const float*)d_in[25];
    const float* dlb      = (const float*)d_in[26];

    // ---- workspace: 48 MiB ----
    float* xe = (float*)d_ws;                    // 2M f32
    float* y  = xe + (size_t)NTOK * E_DIM;       // 2M f32
    u16* xeb  = (u16*)(y + (size_t)NTOK * E_DIM);
    u16* yb   = xeb  + (size_t)NTOK * E_DIM;     // 2M
    u16* qkvb = yb   + (size_t)NTOK * E_DIM;     // 6M
    u16* attb = qkvb + (size_t)NTOK * 3 * E_DIM; // 2M
    u16* ffhb = qkvb;                            // alias (qkvb+attb)
    u16* wt   = attb + (size_t)NTOK * E_DIM;     // 4M u16 = 8 MiB
    u16* vt   = wt;                              // alias: V^T scratch (2M u16), wt dead then

    const size_t WQKV_L = (size_t)3 * 16 * E_DIM * 64;
    const dim3 blk(256);
    const dim3 g_attn(S_LEN / 16, 16, B_SZ);
    const dim3 g_vt(8, 64);
    const dim3 g_qkv(3072 / 128, NTOK / 128);
    const dim3 g_kv(2048 / 128, NTOK / 64);
    const dim3 g_e(1024 / 128, NTOK / 64);
    const dim3 g_ff1(4096 / 128, NTOK / 128);
    const dim3 c_qkv(3072 / 64, 1024 / 64);
    const dim3 c_e(1024 / 64, 1024 / 64);
    const dim3 c_w1(4096 / 64, 1024 / 64);
    const dim3 c_w2(1024 / 64, 4096 / 64);

    transpose_in<<<(NTOK * E_DIM) / 256, blk, 0, stream>>>(src, xe, xeb);
    transpose_in<<<(NTOK * E_DIM) / 256, blk, 0, stream>>>(tgt, y, yb);

    // -------- encoder --------
    for (int i = 0; i < 4; ++i) {
        cvt_wt<true><<<c_qkv, blk, 0, stream>>>(enc_wqkv + i * WQKV_L, wt, 1024, 3072);
        gemm_bt<128, 0><<<g_qkv, blk, 0, stream>>>(xeb, wt, nullptr, nullptr, 0, qkvb, 3072, 1024);
        vt_gen<<<g_vt, blk, 0, stream>>>(qkvb + 2048, vt);
        attn_mfma<true><<<g_attn, blk, 0, stream>>>(qkvb, qkvb + 1024, vt, attb,
                                                    src_mask, src_pad, 0.125f);
        cvt_wt<false><<<c_e, blk, 0, stream>>>(enc_wo + (size_t)i * E_DIM * E_DIM, wt, 1024, 1024);
        gemm_bt<64, 2><<<g_e, blk, 0, stream>>>(attb, wt, enc_bo + i * E_DIM, xe, 1024, xe, 1024, 1024);
        ln_kernel<<<NTOK, blk, 0, stream>>>(xe, enc_lg + (size_t)(i * 2 + 0) * E_DIM,
                                            enc_lb + (size_t)(i * 2 + 0) * E_DIM, xeb);
        cvt_wt<false><<<c_w1, blk, 0, stream>>>(enc_w1 + (size_t)i * E_DIM * DFF_DIM, wt, 1024, 4096);
        gemm_bt<128, 1><<<g_ff1, blk, 0, stream>>>(xeb, wt, enc_b1 + i * DFF_DIM, nullptr, 0, ffhb, 4096, 1024);
        cvt_wt<false><<<c_w2, blk, 0, stream>>>(enc_w2 + (size_t)i * DFF_DIM * E_DIM, wt, 4096, 1024);
        gemm_bt<64, 2><<<g_e, blk, 0, stream>>>(ffhb, wt, enc_b2 + i * E_DIM, xe, 1024, xe, 1024, 4096);
        ln_kernel<<<NTOK, blk, 0, stream>>>(xe, enc_lg + (size_t)(i * 2 + 1) * E_DIM,
                                            enc_lb + (size_t)(i * 2 + 1) * E_DIM, xeb);
    }

    // -------- decoder --------
    for (int i = 0; i < 4; ++i) {
        cvt_wt<true><<<c_qkv, blk, 0, stream>>>(dq_s + i * WQKV_L, wt, 1024, 3072);
        gemm_bt<128, 0><<<g_qkv, blk, 0, stream>>>(yb, wt, nullptr, nullptr, 0, qkvb, 3072, 1024);
        vt_gen<<<g_vt, blk, 0, stream>>>(qkvb + 2048, vt);
        attn_mfma<true><<<g_attn, blk, 0, stream>>>(qkvb, qkvb + 1024, vt, attb,
                                                    tgt_mask, tgt_pad, 0.125f);
        cvt_wt<false><<<c_e, blk, 0, stream>>>(dwo_s + (size_t)i * E_DIM * E_DIM, wt, 1024, 1024);
        gemm_bt<64, 2><<<g_e, blk, 0, stream>>>(attb, wt, dbo_s + i * E_DIM, y, 1024, y, 1024, 1024);
        ln_kernel<<<NTOK, blk, 0, stream>>>(y, dlg + (size_t)(i * 3 + 0) * E_DIM,
                                            dlb + (size_t)(i * 3 + 0) * E_DIM, yb);
        // cross-attention
        cvt_wt<true><<<c_qkv, blk, 0, stream>>>(dq_c + i * WQKV_L, wt, 1024, 3072);
        gemm_bt<64, 0><<<g_e, blk, 0, stream>>>(yb, wt, nullptr, nullptr, 0, qkvb, 3072, 1024);
        gemm_bt<64, 0><<<g_kv, blk, 0, stream>>>(xeb, wt + (size_t)1024 * 1024, nullptr, nullptr, 0,
                                                 qkvb + 1024, 3072, 1024);
        vt_gen<<<g_vt, blk, 0, stream>>>(qkvb + 2048, vt);
        attn_mfma<false><<<g_attn, blk, 0, stream>>>(qkvb, qkvb + 1024, vt, attb,
                                                     nullptr, src_pad, 0.125f);
        cvt_wt<false><<<c_e, blk, 0, stream>>>(dwo_c + (size_t)i * E_DIM * E_DIM, wt, 1024, 1024);
        gemm_bt<64, 2><<<g_e, blk, 0, stream>>>(attb, wt, dbo_c + i * E_DIM, y, 1024, y, 1024, 1024);
        ln_kernel<<<NTOK, blk, 0, stream>>>(y, dlg + (size_t)(i * 3 + 1) * E_DIM,
                                            dlb + (size_t)(i * 3 + 1) * E_DIM, yb);
        // FFN
        cvt_wt<false><<<c_w1, blk, 0, stream>>>(dw1 + (size_t)i * E_DIM * DFF_DIM, wt, 1024, 4096);
        gemm_bt<128, 1><<<g_ff1, blk, 0, stream>>>(yb, wt, db1 + i * DFF_DIM, nullptr, 0, ffhb, 4096, 1024);
        cvt_wt<false><<<c_w2, blk, 0, stream>>>(dw2 + (size_t)i * DFF_DIM * E_DIM, wt, 4096, 1024);
        gemm_bt<64, 2><<<g_e, blk, 0, stream>>>(ffhb, wt, db2 + i * E_DIM, y, 1024, y, 1024, 4096);
        ln_kernel<<<NTOK, blk, 0, stream>>>(y, dlg + (size_t)(i * 3 + 2) * E_DIM,
                                            dlb + (size_t)(i * 3 + 2) * E_DIM, yb);
    }

    writeout<<<(NTOK * E_DIM) / 256, blk, 0, stream>>>(y, (float*)d_out);
}